// Round 7
// baseline (560.347 us; speedup 1.0000x reference)
//
#include <hip/hip_runtime.h>
#include <math.h>

// ---------------------------------------------------------------------------
// Masked attention, split-bf16 MFMA, pre-split planes, 8-wave 4-phase
// double-buffered GEMMs (T2 swizzle + T3/T4 pipelined staging + T5 setprio).
//   convert: x,W -> hi/lo bf16 planes      (scratch in w region of d_out)
//   GEMM1:   planes -> q/k/v hi/lo planes  (bias fused; v planes -> out region)
//   transp:  v planes -> vT planes          (ws)
//   GEMM2:   q,k planes -> scores fp32      (w region, overwrites scratch)
//   softmax: in-place on w; also emits w hi/lo planes over dead q/k planes
//   GEMM4:   wh/wl planes @ vT planes -> out (pure-plane)
// a*b ~= ah*bh + ah*bl + al*bh (3x MFMA, fp32 accumulate).
// LDS tile rows of 32 shorts, slot-swizzled: slot' = kg ^ ((row>>1)&3),
// staged via pre-swizzled global source (global_load_lds writes linearly).
// Verified: SQ_LDS_BANK_CONFLICT == 0 (round 6).
// ---------------------------------------------------------------------------

typedef unsigned short u16;
using bfrag = __attribute__((ext_vector_type(8))) short;
using f32x4 = __attribute__((ext_vector_type(4))) float;

// pack top-16-bits (bf16 truncation) of two fp32 into one dword
__device__ __forceinline__ unsigned pack_hi16(unsigned u0, unsigned u1) {
    return __builtin_amdgcn_perm(u1, u0, 0x07060302u);
}

// split 8 consecutive fp32 into 4 hi-dwords + 4 lo-dwords (2 bf16 each)
__device__ __forceinline__ void split8(const float* f, unsigned* h, unsigned* l) {
    #pragma unroll
    for (int i = 0; i < 4; ++i) {
        const unsigned u0 = __float_as_uint(f[2 * i]);
        const unsigned u1 = __float_as_uint(f[2 * i + 1]);
        h[i] = pack_hi16(u0, u1);
        const float hf0 = __uint_as_float(u0 & 0xffff0000u);
        const float hf1 = __uint_as_float(u1 & 0xffff0000u);
        const unsigned v0 = __float_as_uint(f[2 * i] - hf0);
        const unsigned v1 = __float_as_uint(f[2 * i + 1] - hf1);
        l[i] = pack_hi16(v0, v1);
    }
}

__device__ __forceinline__ void g2lds16(const u16* g, short* l) {
    __builtin_amdgcn_global_load_lds(
        (const __attribute__((address_space(1))) void*)g,
        (__attribute__((address_space(3))) void*)l,
        16, 0, 0);
}

// stage one ROWSx32 bf16 plane tile (8 waves), pre-swizzled global source.
// LDS linear dest: chunk*512 + lane*8 shorts == row*32 + slot*8 for
// row = chunk*16 + (lane>>2), slot = lane&3; source k-group = slot ^ ((row>>1)&3).
template <int ROWS>
__device__ __forceinline__ void stage_plane(
    const u16* __restrict__ g, long ld, short* l, int wave, int lane)
{
    #pragma unroll
    for (int t = 0; t < ROWS / 128; ++t) {
        const int chunk = wave + t * 8;           // 8 waves/round
        const int row = chunk * 16 + (lane >> 2);
        const int g8 = ((lane & 3) ^ ((row >> 1) & 3)) << 3;
        g2lds16(g + (long)row * ld + g8, l + chunk * 512);
    }
}

// read an 8-elem k-fragment for (row, kg) honoring the swizzle
__device__ __forceinline__ bfrag frag_ld(const short* plane, int row, int kg) {
    const int slot = kg ^ ((row >> 1) & 3);
    return *(const bfrag*)(plane + row * 32 + (slot << 3));
}

// ---------------------------------------------------------------------------
// 8-wave (2x4) 4-phase double-buffered plane GEMM.
// C[m][n] = sum_k A[m][k]*B[n][k]; EPI 0: C = acc*scale; EPI 1: qkv-split(+bias).
template <int MREP, int NREP, int EPI>
__global__ __launch_bounds__(512, 2) void gemm8(
    const u16* __restrict__ Ah_g, const u16* __restrict__ Al_g,
    const u16* __restrict__ Bh_g, const u16* __restrict__ Bl_g,
    const float* __restrict__ bias, float* __restrict__ C,
    u16* __restrict__ qh, u16* __restrict__ ql,
    u16* __restrict__ kh, u16* __restrict__ kl,
    u16* __restrict__ vh, u16* __restrict__ vl,
    int K, float scale, int lda, int ldb, int ldc,
    long bsA, long bsB, long bsC)
{
    constexpr int BMt = 2 * MREP * 16;     // 2 waves in M
    constexpr int BNt = 4 * NREP * 16;     // 4 waves in N
    constexpr int ASZ = BMt * 32;          // shorts per A plane tile
    constexpr int BSZ = BNt * 32;
    constexpr int BUF = 2 * ASZ + 2 * BSZ;
    constexpr int MI_PH = MREP / 4;        // mi per phase (4 phases)

    __shared__ __align__(16) short lds[2 * BUF];

    Ah_g += (long)blockIdx.z * bsA;  Al_g += (long)blockIdx.z * bsA;
    Bh_g += (long)blockIdx.z * bsB;  Bl_g += (long)blockIdx.z * bsB;
    if (EPI == 0) C += (long)blockIdx.z * bsC;

    const int tid  = threadIdx.x;
    const int lane = tid & 63;
    const int wave = tid >> 6;
    const int wr = wave >> 2, wc = wave & 3;

    const int row0 = blockIdx.y * BMt;
    const int col0 = blockIdx.x * BNt;

    const u16* At_h = Ah_g + (long)row0 * lda;
    const u16* At_l = Al_g + (long)row0 * lda;
    const u16* Bt_h = Bh_g + (long)col0 * ldb;
    const u16* Bt_l = Bl_g + (long)col0 * ldb;

    f32x4 acc[MREP][NREP];
    const f32x4 fz = {0.f, 0.f, 0.f, 0.f};
    #pragma unroll
    for (int i = 0; i < MREP; ++i)
        #pragma unroll
        for (int j = 0; j < NREP; ++j) acc[i][j] = fz;

    // prologue: stage K-tile 0 into buffer 0
    stage_plane<BMt>(At_h, lda, lds + 0,             wave, lane);
    stage_plane<BMt>(At_l, lda, lds + ASZ,           wave, lane);
    stage_plane<BNt>(Bt_h, ldb, lds + 2 * ASZ,       wave, lane);
    stage_plane<BNt>(Bt_l, ldb, lds + 2 * ASZ + BSZ, wave, lane);
    __syncthreads();

    const int nt  = K / 32;
    const int kg  = lane >> 4;
    const int ar0 = wr * (MREP * 16) + (lane & 15);
    const int bc0 = wc * (NREP * 16) + (lane & 15);
    int cur = 0;

    for (int t = 0; t < nt; ++t) {
        const bool st = (t + 1 < nt);
        short* base  = lds + cur * BUF;
        short* nbase = lds + (cur ^ 1) * BUF;
        const int k1 = (t + 1) * 32;
        const short* sAh = base;
        const short* sAl = base + ASZ;
        const short* sBh = base + 2 * ASZ;
        const short* sBl = base + 2 * ASZ + BSZ;

        bfrag bh[NREP], bl[NREP];
        #pragma unroll
        for (int p = 0; p < 4; ++p) {
            // ---- phase reads (compiler inserts lgkmcnt before MFMA uses) ----
            if (p == 0) {
                #pragma unroll
                for (int nj = 0; nj < NREP; ++nj) {
                    bh[nj] = frag_ld(sBh, bc0 + nj * 16, kg);
                    bl[nj] = frag_ld(sBl, bc0 + nj * 16, kg);
                }
            }
            bfrag ah[MI_PH], al[MI_PH];
            #pragma unroll
            for (int q = 0; q < MI_PH; ++q) {
                const int mi = p * MI_PH + q;
                ah[q] = frag_ld(sAh, ar0 + mi * 16, kg);
                al[q] = frag_ld(sAl, ar0 + mi * 16, kg);
            }
            // ---- issue one plane's prefetch for tile t+1 (stays in flight) ----
            if (st) {
                if (p == 0) stage_plane<BMt>(At_h + k1, lda, nbase, wave, lane);
                if (p == 1) stage_plane<BMt>(At_l + k1, lda, nbase + ASZ, wave, lane);
                if (p == 2) stage_plane<BNt>(Bt_h + k1, ldb, nbase + 2 * ASZ, wave, lane);
                if (p == 3) stage_plane<BNt>(Bt_l + k1, ldb, nbase + 2 * ASZ + BSZ, wave, lane);
            }
            __builtin_amdgcn_s_barrier();
            __builtin_amdgcn_sched_barrier(0);
            __builtin_amdgcn_s_setprio(1);
            #pragma unroll
            for (int q = 0; q < MI_PH; ++q) {
                const int mi = p * MI_PH + q;
                #pragma unroll
                for (int nj = 0; nj < NREP; ++nj) {
                    acc[mi][nj] = __builtin_amdgcn_mfma_f32_16x16x32_bf16(
                        ah[q], bh[nj], acc[mi][nj], 0, 0, 0);
                    acc[mi][nj] = __builtin_amdgcn_mfma_f32_16x16x32_bf16(
                        ah[q], bl[nj], acc[mi][nj], 0, 0, 0);
                    acc[mi][nj] = __builtin_amdgcn_mfma_f32_16x16x32_bf16(
                        al[q], bh[nj], acc[mi][nj], 0, 0, 0);
                }
            }
            __builtin_amdgcn_s_setprio(0);
            __builtin_amdgcn_sched_barrier(0);
            if (p < 3) __builtin_amdgcn_s_barrier();
        }
        // tile boundary: __syncthreads drains vmcnt(0)+lgkmcnt(0) — the 8
        // prefetch loads were covered by the 4 compute phases above.
        if (st) { __syncthreads(); cur ^= 1; }
    }

    // ---- epilogue: C/D layout col=lane&15, row=(lane>>4)*4+r ----
    if (EPI == 0) {
        #pragma unroll
        for (int nj = 0; nj < NREP; ++nj) {
            const int c = col0 + wc * (NREP * 16) + nj * 16 + (lane & 15);
            #pragma unroll
            for (int mi = 0; mi < MREP; ++mi) {
                const int rb = row0 + wr * (MREP * 16) + mi * 16 + (lane >> 4) * 4;
                #pragma unroll
                for (int r = 0; r < 4; ++r)
                    C[(long)(rb + r) * ldc + c] = acc[mi][nj][r] * scale;
            }
        }
    } else {
        // split into q/k/v planes; tile is 256-wide -> never crosses a boundary
        u16 *ph, *pl;
        int coff;
        if (col0 >= 2048)      { ph = vh; pl = vl; coff = 2048; }
        else if (col0 >= 1024) { ph = kh; pl = kl; coff = 1024; }
        else                   { ph = qh; pl = ql; coff = 0; }
        #pragma unroll
        for (int nj = 0; nj < NREP; ++nj) {
            const int c = col0 + wc * (NREP * 16) + nj * 16 + (lane & 15);
            const float bv = bias[c];
            const int cl = c - coff;
            #pragma unroll
            for (int mi = 0; mi < MREP; ++mi) {
                const int rb = row0 + wr * (MREP * 16) + mi * 16 + (lane >> 4) * 4;
                #pragma unroll
                for (int r = 0; r < 4; ++r) {
                    const float val = acc[mi][nj][r] + bv;
                    const unsigned u = __float_as_uint(val);
                    const float fh = __uint_as_float(u & 0xffff0000u);
                    const long idx = (long)(rb + r) * 1024 + cl;
                    ph[idx] = (u16)(u >> 16);
                    pl[idx] = (u16)(__float_as_uint(val - fh) >> 16);
                }
            }
        }
    }
}

// ---------------------------------------------------------------------------
// convert fp32 -> hi/lo bf16 planes (flat)
__global__ __launch_bounds__(256) void convert_split(
    const float* __restrict__ in, u16* __restrict__ hi, u16* __restrict__ lo,
    long n8)
{
    const long i = (long)blockIdx.x * blockDim.x + threadIdx.x;
    if (i >= n8) return;
    float f[8];
    *(float4*)&f[0] = ((const float4*)in)[i * 2];
    *(float4*)&f[4] = ((const float4*)in)[i * 2 + 1];
    unsigned h[4], l[4];
    split8(f, h, l);
    *(uint4*)&hi[i * 8] = make_uint4(h[0], h[1], h[2], h[3]);
    *(uint4*)&lo[i * 8] = make_uint4(l[0], l[1], l[2], l[3]);
}

// ---------------------------------------------------------------------------
// transpose v planes [8192][1024] -> vT planes [1024][8192]
__global__ __launch_bounds__(256) void transpose_v(
    const u16* __restrict__ vh, const u16* __restrict__ vl,
    u16* __restrict__ vTh, u16* __restrict__ vTl)
{
    __shared__ u16 tile[64][72];
    const u16* __restrict__ src = blockIdx.z ? vl : vh;
    u16* __restrict__ dst       = blockIdx.z ? vTl : vTh;

    const int d0 = blockIdx.x * 64;
    const int s0 = blockIdx.y * 64;
    const int t = threadIdx.x;
    const int r = t >> 2, cseg = (t & 3) * 16;

    *(uint4*)&tile[r][cseg]     = *(const uint4*)&src[(long)(s0 + r) * 1024 + d0 + cseg];
    *(uint4*)&tile[r][cseg + 8] = *(const uint4*)&src[(long)(s0 + r) * 1024 + d0 + cseg + 8];
    __syncthreads();

    u16 tmp[16];
    #pragma unroll
    for (int j = 0; j < 16; ++j) tmp[j] = tile[cseg + j][r];
    *(uint4*)&dst[(long)(d0 + r) * 8192 + s0 + cseg]     = *(uint4*)&tmp[0];
    *(uint4*)&dst[(long)(d0 + r) * 8192 + s0 + cseg + 8] = *(uint4*)&tmp[8];
}

// ---------------------------------------------------------------------------
// row softmax, one block per row of 2048; also emits w hi/lo planes for GEMM4
__global__ __launch_bounds__(256) void softmax_kernel(
    float* __restrict__ w, u16* __restrict__ wh, u16* __restrict__ wl)
{
    const long row = blockIdx.x;
    float* p = w + row * 2048;
    const int tid = threadIdx.x;

    float v[8];
    float m = -INFINITY;
    #pragma unroll
    for (int i = 0; i < 8; ++i) {
        v[i] = p[tid + i * 256];
        m = fmaxf(m, v[i]);
    }
    #pragma unroll
    for (int off = 32; off > 0; off >>= 1)
        m = fmaxf(m, __shfl_xor(m, off));

    __shared__ float redm[4];
    __shared__ float reds[4];
    const int wave = tid >> 6;
    if ((tid & 63) == 0) redm[wave] = m;
    __syncthreads();
    m = fmaxf(fmaxf(redm[0], redm[1]), fmaxf(redm[2], redm[3]));

    float s = 0.f;
    #pragma unroll
    for (int i = 0; i < 8; ++i) {
        v[i] = __expf(v[i] - m);
        s += v[i];
    }
    #pragma unroll
    for (int off = 32; off > 0; off >>= 1)
        s += __shfl_xor(s, off);
    if ((tid & 63) == 0) reds[wave] = s;
    __syncthreads();
    s = reds[0] + reds[1] + reds[2] + reds[3];

    const float inv = 1.0f / s;
    #pragma unroll
    for (int i = 0; i < 8; ++i) {
        const float y = v[i] * inv;
        const long idx = row * 2048 + tid + i * 256;
        w[idx] = y;
        const unsigned u = __float_as_uint(y);
        const float fh = __uint_as_float(u & 0xffff0000u);
        wh[idx] = (u16)(u >> 16);
        wl[idx] = (u16)(__float_as_uint(y - fh) >> 16);
    }
}

// ---------------------------------------------------------------------------
extern "C" void kernel_launch(void* const* d_in, const int* in_sizes, int n_in,
                              void* d_out, int out_size, void* d_ws, size_t ws_size,
                              hipStream_t stream)
{
    constexpr int B = 4, S = 2048, D = 1024;
    constexpr long BS = (long)B * S;          // 8192
    constexpr long P = BS * D;                // 8388608 elems per q/k/v plane

    const float* x  = (const float*)d_in[0];  // [8192,1024]
    const float* W  = (const float*)d_in[1];  // [3072,1024]
    const float* bq = (const float*)d_in[2];  // [3072]

    float* out = (float*)d_out;               // [8192,1024] fp32
    float* w   = out + P;                     // [4,2048,2048] fp32

    // ws: q/k planes + vT planes (6 x 16.78 MB = 100.66 MB)
    u16* wsu = (u16*)d_ws;
    u16 *qh = wsu,       *ql = qh + P;
    u16 *kh = ql + P,    *kl = kh + P;
    u16 *vTh = kl + P,   *vTl = vTh + P;
    // after GEMM2, q/k planes are dead -> reuse for w planes (2 x 33.55 MB)
    u16 *wh = wsu,       *wl = wsu + 2 * P;

    // scratch planes inside the (not yet written) w region: 46.1 MB < 67.1 MB
    u16* wscr = (u16*)w;
    u16 *xh = wscr,      *xl = xh + P;
    u16 *Wh = xl + P,    *Wl = Wh + 3 * D * D;

    // v planes (s-major) in the (not yet written) out region: exactly 33.55 MB
    u16 *vh = (u16*)out, *vl = vh + P;

    // 1) convert x, W to planes
    convert_split<<<dim3((unsigned)(P / 8 / 256)), 256, 0, stream>>>(x, xh, xl, P / 8);
    convert_split<<<dim3((unsigned)(3 * D * D / 8 / 256)), 256, 0, stream>>>(
        W, Wh, Wl, 3 * D * D / 8);

    // 2) GEMM1: qkv planes = split(x @ W^T + b)   (BM=128, BN=256; 768 blocks)
    gemm8<4, 4, 1><<<dim3(3 * D / 256, BS / 128, 1), 512, 0, stream>>>(
        xh, xl, Wh, Wl, bq, nullptr,
        qh, ql, kh, kl, vh, vl,
        D, 1.0f, D, D, 0, 0, 0, 0);

    // 3) transpose v planes -> vT planes
    transpose_v<<<dim3(D / 64, BS / 64, 2), 256, 0, stream>>>(vh, vl, vTh, vTl);

    // 4) GEMM2: scores = q @ k^T / 32   (BM=BN=256; 256 blocks)
    gemm8<8, 4, 0><<<dim3(S / 256, S / 256, B), 512, 0, stream>>>(
        qh, ql, kh, kl, nullptr, w,
        nullptr, nullptr, nullptr, nullptr, nullptr, nullptr,
        D, 1.0f / 32.0f, D, D, S,
        (long)S * D, (long)S * D, (long)S * S);

    // 5) softmax rows of w in-place; emit wh/wl planes (over dead q/k planes)
    softmax_kernel<<<(int)BS, 256, 0, stream>>>(w, wh, wl);

    // 6) GEMM4: out = w @ v   (BM=256, BN=128; 256 blocks; pure-plane)
    gemm8<8, 2, 0><<<dim3(D / 128, S / 256, B), 512, 0, stream>>>(
        wh, wl, vTh, vTl, nullptr, out,
        nullptr, nullptr, nullptr, nullptr, nullptr, nullptr,
        S, 1.0f, S, (int)BS, D,
        (long)S * S, (long)S, (long)S * D);
}